// Round 10
// baseline (688.286 us; speedup 1.0000x reference)
//
#include <hip/hip_runtime.h>

// CTC prefix beam search, MI355X. One wave per batch element; latency-bound
// serial scan. R10 = R9 + dependency-chain and state-width cuts:
//   (a) state slimmed: h2/ph2 kept ONLY as 26-bit fields (the match has
//       compared h2&M26 since R4, and low-26 of h2*69069+c is closed under
//       the update); lastb lives in p2[31:26] (empty == 0: ext winners
//       always have cnew in [1,63] since lane-0/blank is BIGNEG-gated and
//       BIGNEG is never selectable); lenb REMOVED from scan state -- length
//       recomputed at traceback by counting extend entries. State gather:
//       7 -> 6 bpermutes, fewer per-step VALU.
//   (b) mi match accumulated as a bitmask (or-tree, reassociable) instead
//       of a 16-deep serial cndmask chain; mi = ctz(mbits).
//   (c) scatter positions computed independently per s via
//       popc(sm & ((1<<s)-1)) -- kills the 17-deep pos+= serial chain.
//   (d) traceback fills an LDS scratch right-to-left (single pointer chase,
//       counts length), then all 64 lanes copy shifted -> labels + lens.
//   (e) softmax: 4 rows per 256-thread block (2048 blocks, was 8192).
// R9 retained: pre-clear slots, per-lane dump slots, half-rank (totc<=16),
// tot=val carry, fused speculative scatter, sparse merge loop.
// Exactness: selection is the exact stable top-16 (pack_key tie-break =
// lax.top_k order); merged is bit-identical (1-element logsumexp = value).

#define T_MAX 256
#define BATCH 32
#define NC 64
#define BEAM 16
#define TOPK 4
#define NEG (-1.0e9f)
#define BIGNEG (-2.0e9f)
#define FLTMAX 3.402823466e+38f
#define M26 0x03FFFFFFu

typedef unsigned long long u64;
typedef unsigned int u32;

// Matches jnp.logaddexp exactly: max + log1p(exp(-|a-b|))
__device__ __forceinline__ float log_add_exp(float a, float b) {
    float m = fmaxf(a, b);
    float d = fabsf(a - b);
    return m + log1pf(expf(-d));
}

// Wave-uniform lane reads: VALU->SGPR, no DS pipe.
__device__ __forceinline__ u32 rdl_u32(u32 v, int sl) {
    return (u32)__builtin_amdgcn_readlane((int)v, sl);
}
__device__ __forceinline__ float rdl_f(float v, int sl) {
    return __uint_as_float(rdl_u32(__float_as_uint(v), sl));
}
__device__ __forceinline__ int rdl_i(int v, int sl) {
    return __builtin_amdgcn_readlane(v, sl);
}
// popcount of 64-bit mask strictly below this lane
__device__ __forceinline__ u32 mbcnt64(u64 m) {
    return __builtin_amdgcn_mbcnt_hi((u32)(m >> 32),
           __builtin_amdgcn_mbcnt_lo((u32)m, 0u));
}

// u64 key: monotone float in [42:11], fl = 2047-flat in [10:0].
// Larger key == (larger value, then smaller flat) -> lax.top_k stable order.
// All real keys > 0, so 0 is a safe null (sinks in descending order).
__device__ __forceinline__ u64 pack_key_fl(float v, u32 fl) {
    u32 u = __float_as_uint(v);
    u32 m = u ^ ((u32)((int)u >> 31) | 0x80000000u);
    return ((u64)m << 11) | (u64)fl;
}
__device__ __forceinline__ u64 pack_key(float v, int flat) {
    return pack_key_fl(v, (u32)(2047 - flat));
}
__device__ __forceinline__ float key_val(u64 key) {
    u32 k = (u32)(key >> 11);
    u32 u = (k & 0x80000000u) ? (k ^ 0x80000000u) : ~k;
    return __uint_as_float(u);
}
__device__ __forceinline__ int key_flat(u64 key) {
    return 2047 - (int)(key & 2047u);
}
__device__ __forceinline__ u64 max64(u64 a, u64 b) { return a > b ? a : b; }
__device__ __forceinline__ u64 min64(u64 a, u64 b) { return a < b ? a : b; }

// Bitonic sort of 16 register-resident u64 keys, descending (overflow fallback).
__device__ __forceinline__ void sort16_desc_u64(u64 (&a)[BEAM]) {
    #pragma unroll
    for (int k = 2; k <= 16; k <<= 1) {
        #pragma unroll
        for (int j = k >> 1; j > 0; j >>= 1) {
            #pragma unroll
            for (int i = 0; i < 16; ++i) {
                int l = i ^ j;
                if (l > i) {
                    const bool desc = ((i & k) == 0);
                    u64 x = a[i], y = a[l];
                    bool sw = desc ? (x < y) : (x > y);
                    a[i] = sw ? y : x;
                    a[l] = sw ? x : y;
                }
            }
        }
    }
}

// Bitonic sort of 16 register-resident f32 values, descending.
__device__ __forceinline__ void sort16_desc_f32(float (&a)[BEAM]) {
    #pragma unroll
    for (int k = 2; k <= 16; k <<= 1) {
        #pragma unroll
        for (int j = k >> 1; j > 0; j >>= 1) {
            #pragma unroll
            for (int i = 0; i < 16; ++i) {
                int l = i ^ j;
                if (l > i) {
                    const bool desc = ((i & k) == 0);
                    float x = a[i], y = a[l];
                    float mx = fmaxf(x, y), mn = fminf(x, y);
                    a[i] = desc ? mx : mn;
                    a[l] = desc ? mn : mx;
                }
            }
        }
    }
}

// One value-only butterfly merge level (exact-phase-1 fallback).
template <int M>
__device__ __forceinline__ void bf_level_f32(float (&a)[BEAM]) {
    float c[BEAM];
    #pragma unroll
    for (int i = 0; i < BEAM; ++i)
        c[i] = __shfl_xor(a[BEAM - 1 - i], M, 64);
    #pragma unroll
    for (int i = 0; i < BEAM; ++i)
        c[i] = fmaxf(a[i], c[i]);
    #pragma unroll
    for (int j = 8; j > 0; j >>= 1) {
        #pragma unroll
        for (int i = 0; i < BEAM; ++i)
            if ((i & j) == 0) {
                float x = c[i], y = c[i | j];
                c[i]     = fmaxf(x, y);
                c[i | j] = fminf(x, y);
            }
    }
    #pragma unroll
    for (int i = 0; i < BEAM; ++i) a[i] = c[i];
}

// Fully parallel log-softmax precompute: one wave per (t,b) row, 4 rows/block.
// Also emits rowmax = max_c logp = -log(sum) for the beam kernel's anchor.
__global__ __launch_bounds__(256) void softmax_kernel(const float* __restrict__ data,
                                                      float* __restrict__ lp_out,
                                                      float* __restrict__ rm_out) {
    const int row = blockIdx.x * 4 + (threadIdx.x >> 6);
    const int lane = threadIdx.x & 63;
    float x = data[row * NC + lane];
    float mx = x;
    #pragma unroll
    for (int m = 1; m < 64; m <<= 1) mx = fmaxf(mx, __shfl_xor(mx, m, 64));
    float sum = expf(x - mx);
    #pragma unroll
    for (int m = 1; m < 64; m <<= 1) sum += __shfl_xor(sum, m, 64);
    float ls = logf(sum);
    lp_out[row * NC + lane] = (x - mx) - ls;
    if (lane == 0) rm_out[row] = -ls;
}

template <bool PRE>
__global__ __launch_bounds__(64, 1) void ctc_beam_kernel(
        const float* __restrict__ data,      // [T, B, C] logits
        const float* __restrict__ lp_pre,    // [T, B, C] log-probs (if PRE)
        const float* __restrict__ rm_pre,    // [T, B] row max logp (if PRE)
        const int*   __restrict__ data_len,  // [B]
        float*       __restrict__ out)       // [B*4 probs][B*4 lens][B*4*256 labels]
{
    const int b    = blockIdx.x;
    const int lane = threadIdx.x;

    __shared__ __align__(16) u64 slotsL[128];     // [0,64) slots; [64,128) per-lane dump
    __shared__ unsigned short hist[T_MAX * BEAM]; // [11:8]=parent, bit7=stay, [6:0]=char
    __shared__ unsigned char scr[TOPK * T_MAX];   // traceback label scratch
    __shared__ int ord4[TOPK];
    __shared__ float val4[TOPK];
    __shared__ int cnt4[TOPK];

    int len = data_len[b];
    if (len < 0) len = 0;
    if (len > T_MAX) len = T_MAX;

    // ---- beam state in registers (meaningful in lanes < 16) ----
    // p2 = h2_low26 | (lastb << 26); lastb==0 <=> empty prefix.
    float pb  = (lane == 0) ? 0.0f : NEG;
    float pnb = NEG;
    float tot = log_add_exp(pb, pnb);  // carried; inside loop tot == val (bit-exact)
    u32 h1 = 0u, p2 = 0u;        // full-prefix hash (h1 32b, h2 26b in p2)
    u32 ph1 = 0u, ph2m = 0u;     // parent-prefix hash (h1 32b, h2 26b)
    float spread = 1.0e30f;      // forces exact path at t=0
    float v1prev = 0.0f;

    const float* src = PRE ? lp_pre : data;
    float xpref = (len > 0) ? src[b * NC + lane] : 0.f;          // prefetch row 0
    float rmpref = (PRE && len > 0) ? rm_pre[b] : 0.f;           // rowmax[0,b]

    #pragma unroll 1
    for (int t = 0; t < len; ++t) {
        float x = xpref;
        float rm = rmpref;
        int tn = (t + 1 < len) ? (t + 1) : t;
        xpref = src[(tn * BATCH + b) * NC + lane];   // prefetch next row early
        if (PRE) rmpref = rm_pre[tn * BATCH + b];

        // pre-clear selection slots: drains under the long VALU phase below;
        // after a good scatter, slots [totc,64) are null with no pad stage.
        slotsL[lane] = 0ull;

        float lp;
        if (PRE) {
            lp = x;
        } else {
            float mx = x;
            #pragma unroll
            for (int m = 1; m < 64; m <<= 1) mx = fmaxf(mx, __shfl_xor(mx, m, 64));
            float sum = expf(x - mx);
            #pragma unroll
            for (int m = 1; m < 64; m <<= 1) sum += __shfl_xor(sum, m, 64);
            float ls = logf(sum);
            lp = (x - mx) - ls;
            rm = -ls;
        }
        float lp0 = rdl_f(lp, 0);

        // ---- stay candidates (lanes < 16 meaningful) ----
        int lastc = (int)(p2 >> 26);                 // 0 == empty
        float lplast = __shfl(lp, lastc, 64);        // variable lane: bpermute
        float st_pb   = tot + lp0;
        float st_pnb0 = (lastc != 0) ? (pnb + lplast) : NEG;

        float lpx = (lane == 0) ? BIGNEG : lp;       // blank-ext gate, hoisted

        // ---- fused per-beam loop: extends + parent-hash match (bitmask) ----
        float e0s[BEAM];
        u32 mbits = 0u;
        #pragma unroll
        for (int i = 0; i < BEAM; ++i) {
            float tot_i = rdl_f(tot, i);
            float pb_i  = rdl_f(pb, i);
            u32   h1_i  = rdl_u32(h1, i);
            u32   p2_i  = rdl_u32(p2, i);
            int last_i = (int)(p2_i >> 26);
            e0s[i] = ((lane == last_i) ? pb_i : tot_i) + lpx;
            mbits |= (ph1 == h1_i && ph2m == (p2_i & M26)) ? (1u << i) : 0u;
        }

        // ---- duplicate-prefix fold: sparse wave-uniform loop ----
        bool jm = (lane < BEAM) && (lastc != 0) && (mbits != 0u);
        u64 mm = __ballot(jm);
        float merged = NEG;
        float st_pnb;
        if (mm) {
            u32 excl = 0u;
            int mi = (int)__builtin_ctz(mbits | 0x10000u);   // safe when mbits==0
            int mpack = ((mi & 15) << 6) | lastc;
            u64 mw = mm;
            while (mw) {
                int j = (int)__builtin_ctzll(mw);
                mw &= mw - 1;
                int pk = rdl_i(mpack, j);            // dynamic uniform lane
                int i  = (pk >> 6) & 15;
                int c  = pk & 63;
                float tot_i = rdl_f(tot, i);
                float pb_i  = rdl_f(pb, i);
                int   l_i   = (int)(rdl_u32(p2, i) >> 26);
                float lp_c  = rdl_f(lp, c);
                float mv = ((c == l_i) ? pb_i : tot_i) + lp_c;  // == e0s[i]@lane c
                if (lane == j) merged = mv;
                if (lane == c) excl |= (1u << i);    // exclude ext(i,c)
            }
            #pragma unroll
            for (int s = 0; s < BEAM; ++s)
                if ((excl >> s) & 1u) e0s[s] = BIGNEG;
            st_pnb = log_add_exp(st_pnb0, merged);
        } else {
            st_pnb = st_pnb0;   // lae(x, NEG) == x bit-exact for real x
        }
        float st_tot = log_add_exp(st_pb, st_pnb);

        // ---- fused speculative scatter: survivor bitmask + independent
        //      positions (popc-prefix), one pass. Dumps go to 64+lane. ----
        auto do_scatter = [&](float th) -> u32 {
            u32 sm = 0u;
            #pragma unroll
            for (int s = 0; s < BEAM; ++s)
                sm |= (e0s[s] >= th) ? (1u << s) : 0u;
            bool stw = (lane < BEAM) && (st_tot >= th);
            u32 mycnt = (u32)__popc(sm) + (stw ? 1u : 0u);
            u32 base = 0;
            #pragma unroll
            for (int k = 0; k < 5; ++k)
                base += mbcnt64(__ballot(((mycnt >> k) & 1u) != 0u)) << k;
            u32 totc = rdl_u32(base + mycnt, 63);
            u32 dump = (64u + (u32)lane) << 3;
            u32 fl = 2031u - (u32)lane;          // 2047 - (BEAM + 0*NC + lane)
            #pragma unroll
            for (int s = 0; s < BEAM; ++s) {
                u32 pos = base + (u32)__popc(sm & ((1u << s) - 1u));
                bool w = ((sm >> s) & 1u) && (pos < 64u);
                u32 a = w ? (pos << 3) : dump;
                *(u64*)((char*)slotsL + a) = pack_key_fl(e0s[s], fl);
                fl -= 64u;
            }
            {
                u32 spos = base + (u32)__popc(sm);
                u32 a = (stw && spos < 64u) ? (spos << 3) : dump;
                *(u64*)((char*)slotsL + a) = pack_key_fl(st_tot, 2047u - (u32)lane);
            }
            return totc;
        };

        float A = v1prev + rm;
        u32 totc = do_scatter(A - spread);
        if (totc < BEAM || totc > 32u) {
            float th2 = (totc > 32u) ? (A - 0.45f * spread)
                                     : (A - (2.5f * spread + 1.0f));
            slotsL[lane] = 0ull;                 // re-clear stale survivors
            asm volatile("" ::: "memory");
            totc = do_scatter(th2);
            if (totc < BEAM || totc > 32u) {
                // ---- exact phase-1: v16 = 16th-largest of the true multiset ----
                float a[BEAM];
                #pragma unroll
                for (int s = 0; s < BEAM; ++s) a[s] = e0s[s];
                sort16_desc_f32(a);
                {   // fold stay value into local sorted list
                    float sv = (lane < BEAM) ? st_tot : NEG;
                    #pragma unroll
                    for (int i = BEAM - 1; i >= 1; --i)
                        a[i] = fmaxf(a[i], fminf(a[i - 1], sv));
                    a[0] = fmaxf(a[0], sv);
                }
                bf_level_f32<1>(a);  bf_level_f32<2>(a);  bf_level_f32<4>(a);
                bf_level_f32<8>(a);  bf_level_f32<16>(a); bf_level_f32<32>(a);
                slotsL[lane] = 0ull;             // re-clear stale survivors
                asm volatile("" ::: "memory");
                totc = do_scatter(a[15]);        // totc in [16,32] by construction
            }
        }

        int flat; float val;
        if (totc <= 32u) {
            asm volatile("" ::: "memory");   // single wave: in-order LDS
            u64 mk = slotsL[lane];
            u32 rank = 0;                    // #keys strictly greater
            const uint4* q4 = (const uint4*)slotsL;
            if (totc <= 16u) {               // slots 16-31 provably null
                #pragma unroll
                for (int q = 0; q < 8; ++q) {
                    uint4 w = q4[q];
                    u64 ka = ((u64)w.y << 32) | w.x;
                    u64 kb = ((u64)w.w << 32) | w.z;
                    rank += (ka > mk) ? 1u : 0u;
                    rank += (kb > mk) ? 1u : 0u;
                }
            } else {
                #pragma unroll
                for (int q = 0; q < 16; ++q) {   // 32 keys = 16 x 16B
                    uint4 w = q4[q];
                    u64 ka = ((u64)w.y << 32) | w.x;
                    u64 kb = ((u64)w.w << 32) | w.z;
                    rank += (ka > mk) ? 1u : 0u;
                    rank += (kb > mk) ? 1u : 0u;
                }
            }
            // push-by-rank: lane r receives the rank-r key (ranks unique,
            // keys strictly distinct via flat tie-break)
            int selhi = 0, sello = 0;
            if (lane < (int)totc) {
                selhi = __builtin_amdgcn_ds_permute((int)(rank << 2),
                                                    (int)(mk >> 32));
                sello = __builtin_amdgcn_ds_permute((int)(rank << 2),
                                                    (int)(mk & 0xFFFFFFFFu));
            }
            u64 sel = ((u64)(u32)selhi << 32) | (u32)sello;
            flat = key_flat(sel);
            val  = key_val(sel);
        } else {
            // ---- exact u64 register fallback (tie storm), ~never ----
            u64 ku[BEAM];
            #pragma unroll
            for (int s = 0; s < BEAM; ++s)
                ku[s] = pack_key(e0s[s], BEAM + s * NC + lane);
            sort16_desc_u64(ku);
            u64 sk = (lane < BEAM) ? pack_key(st_tot, lane) : 0ull;
            #pragma unroll
            for (int i = BEAM - 1; i >= 1; --i)
                ku[i] = max64(ku[i], min64(ku[i - 1], sk));
            ku[0] = max64(ku[0], sk);
            #pragma unroll 1
            for (int m = 1; m < 64; m <<= 1) {
                u64 c_[BEAM];
                #pragma unroll
                for (int i = 0; i < BEAM; ++i) {
                    u64 o = (u64)__shfl_xor((long long)ku[BEAM - 1 - i], m, 64);
                    c_[i] = max64(ku[i], o);
                }
                #pragma unroll
                for (int j = 8; j > 0; j >>= 1) {
                    #pragma unroll
                    for (int i = 0; i < BEAM; ++i)
                        if ((i & j) == 0) {
                            u64 xk = c_[i], yk = c_[i | j];
                            bool sw = xk < yk;
                            c_[i]     = sw ? yk : xk;
                            c_[i | j] = sw ? xk : yk;
                        }
                }
                #pragma unroll
                for (int i = 0; i < BEAM; ++i) ku[i] = c_[i];
            }
            u64 selkey = ku[0];
            #pragma unroll
            for (int i = 1; i < BEAM; ++i)
                if (lane == i) selkey = ku[i];
            flat = key_flat(selkey);
            val  = key_val(selkey);
        }

        // ---- predictor update from the EXACT selection (any path) ----
        {
            float v1n  = rdl_f(val, 0);
            float v16n = rdl_f(val, 15);
            spread = (fmaxf(A, v1n) - v16n) * 1.25f + 1.0e-3f;
            v1prev = v1n;
        }

        // ---- new state (lane k = rank-k winner) ----
        bool stay = flat < BEAM;
        int pidx = (stay ? flat : ((flat - BEAM) >> 6)) & 15;
        int cnew = stay ? 0 : ((flat - BEAM) & 63);

        // variable-index gathers (bpermute), all independent -> one wait
        float g_stpb  = __shfl(st_pb, pidx, 64);
        float g_stpnb = __shfl(st_pnb, pidx, 64);
        u32   g_h1    = (u32)__shfl((int)h1, pidx, 64);
        u32   g_p2    = (u32)__shfl((int)p2, pidx, 64);
        u32   g_ph1   = (u32)__shfl((int)ph1, pidx, 64);
        u32   g_ph2m  = (u32)__shfl((int)ph2m, pidx, 64);

        pb   = stay ? g_stpb : NEG;
        pnb  = stay ? g_stpnb : val;
        tot  = val;                      // == lae(pb,pnb) bit-exactly
        u32 h2n = (((g_p2 & M26) * 69069u + (u32)(cnew + 1)) & M26)
                | ((u32)cnew << 26);
        h1   = stay ? g_h1 : (g_h1 * 1000003u + (u32)(cnew + 1));
        p2   = stay ? g_p2 : h2n;
        ph1  = stay ? g_ph1 : g_h1;      // parent-hash of new prefix
        ph2m = stay ? g_ph2m : (g_p2 & M26);
        if (lane < BEAM)
            hist[t * BEAM + lane] =
                (unsigned short)((pidx << 8) | (stay ? 0x80 : 0) | cnew);
    }
    __syncthreads();

    // ---- final stable top-4 over beam totals ----
    float ft = (lane < BEAM) ? log_add_exp(pb, pnb) : -FLTMAX;
    int fidx = (lane < BEAM) ? lane : 0x7FFFFFFF;
    for (int k = 0; k < TOPK; ++k) {
        float bv = ft; int bi = fidx;
        #pragma unroll
        for (int m = 1; m < 64; m <<= 1) {
            float ov = __shfl_xor(bv, m, 64);
            int   oi = __shfl_xor(bi, m, 64);
            if (ov > bv || (ov == bv && oi < bi)) { bv = ov; bi = oi; }
        }
        if (lane == 0) { ord4[k] = bi; val4[k] = bv; }
        if (lane == bi) ft = -FLTMAX;
    }
    __syncthreads();

    // ---- traceback: single pointer chase per path; labels right-aligned in
    //      scratch; length = #extend entries. Then parallel shifted copy. ----
    if (lane < TOPK) {
        const int k = lane;
        int cur = ord4[k] & 15;
        int rp = T_MAX, c = 0;
        for (int tt = len - 1; tt >= 0; --tt) {
            unsigned short h = hist[tt * BEAM + cur];
            if (!(h & 0x80)) { scr[k * T_MAX + (--rp)] = (unsigned char)(h & 0x7F); ++c; }
            cur = h >> 8;
        }
        cnt4[k] = c;
        out[b * TOPK + k] = -val4[k];
        out[BATCH * TOPK + b * TOPK + k] = (float)c;
    }
    __syncthreads();
    for (int e2 = lane; e2 < TOPK * T_MAX; e2 += 64) {
        int k = e2 >> 8;                  // T_MAX == 256
        int p = e2 & (T_MAX - 1);
        int c = cnt4[k];
        float v = (p < c) ? (float)scr[k * T_MAX + T_MAX - c + p] : -1.0f;
        out[BATCH * TOPK * 2 + b * (TOPK * T_MAX) + k * T_MAX + p] = v;
    }
}

extern "C" void kernel_launch(void* const* d_in, const int* in_sizes, int n_in,
                              void* d_out, int out_size, void* d_ws, size_t ws_size,
                              hipStream_t stream) {
    const float* data = (const float*)d_in[0];
    const int* data_len = (const int*)d_in[1];
    float* out = (float*)d_out;
    const size_t lp_bytes = (size_t)T_MAX * BATCH * NC * sizeof(float);
    const size_t rm_bytes = (size_t)T_MAX * BATCH * sizeof(float);
    if (ws_size >= lp_bytes + rm_bytes) {
        float* lp_ws = (float*)d_ws;
        float* rm_ws = lp_ws + (size_t)T_MAX * BATCH * NC;
        softmax_kernel<<<dim3(T_MAX * BATCH / 4), dim3(256), 0, stream>>>(data, lp_ws, rm_ws);
        ctc_beam_kernel<true><<<dim3(BATCH), dim3(64), 0, stream>>>(data, lp_ws, rm_ws, data_len, out);
    } else {
        ctc_beam_kernel<false><<<dim3(BATCH), dim3(64), 0, stream>>>(data, nullptr, nullptr, data_len, out);
    }
}

// Round 11
// 590.067 us; speedup vs baseline: 1.1665x; 1.1665x over previous
//
#include <hip/hip_runtime.h>

// CTC prefix beam search, MI355X. One wave per batch element; latency-bound
// serial scan. R11 = R9 VERBATIM (proven best: kernel 537us, absmax 0.0).
// R10's restructurings (bitmask match, popc-prefix scatter, slimmed state)
// kept total VALU issue constant but added ~100us of pure scheduling stall
// (VALUBusy*dur invariant ~435 across R5/R9/R10) -- single-wave kernels
// have no second wave to absorb codegen bubbles, so R9's instruction mix,
// which the compiler schedules well, is the keeper.
// Structure: R5 base + pre-clear slots + per-lane dump slots + half-rank.
//   - tot = val carry (next tot == selection value, bit-exact)
//   - fused speculative scatter (anchor threshold + count-in-[16,32] guard)
//   - sparse wave-uniform merge loop (readlane-only, no DS)
//   - rank-selection via LDS broadcast compare + ds_permute push-by-rank
//   - exact u64 register-sort fallback for tie storms
// Exactness: selection is the exact stable top-16 (pack_key tie-break =
// lax.top_k order); merged is bit-identical (1-element logsumexp = value).

#define T_MAX 256
#define BATCH 32
#define NC 64
#define BEAM 16
#define TOPK 4
#define NEG (-1.0e9f)
#define BIGNEG (-2.0e9f)
#define FLTMAX 3.402823466e+38f

typedef unsigned long long u64;
typedef unsigned int u32;

// Matches jnp.logaddexp exactly: max + log1p(exp(-|a-b|))
__device__ __forceinline__ float log_add_exp(float a, float b) {
    float m = fmaxf(a, b);
    float d = fabsf(a - b);
    return m + log1pf(expf(-d));
}

// Wave-uniform lane reads: VALU->SGPR, no DS pipe.
__device__ __forceinline__ u32 rdl_u32(u32 v, int sl) {
    return (u32)__builtin_amdgcn_readlane((int)v, sl);
}
__device__ __forceinline__ float rdl_f(float v, int sl) {
    return __uint_as_float(rdl_u32(__float_as_uint(v), sl));
}
__device__ __forceinline__ int rdl_i(int v, int sl) {
    return __builtin_amdgcn_readlane(v, sl);
}
// popcount of 64-bit mask strictly below this lane
__device__ __forceinline__ u32 mbcnt64(u64 m) {
    return __builtin_amdgcn_mbcnt_hi((u32)(m >> 32),
           __builtin_amdgcn_mbcnt_lo((u32)m, 0u));
}

// u64 key: monotone float in [42:11], fl = 2047-flat in [10:0].
// Larger key == (larger value, then smaller flat) -> lax.top_k stable order.
// All real keys > 0, so 0 is a safe null (sinks in descending order).
__device__ __forceinline__ u64 pack_key_fl(float v, u32 fl) {
    u32 u = __float_as_uint(v);
    u32 m = u ^ ((u32)((int)u >> 31) | 0x80000000u);
    return ((u64)m << 11) | (u64)fl;
}
__device__ __forceinline__ u64 pack_key(float v, int flat) {
    return pack_key_fl(v, (u32)(2047 - flat));
}
__device__ __forceinline__ float key_val(u64 key) {
    u32 k = (u32)(key >> 11);
    u32 u = (k & 0x80000000u) ? (k ^ 0x80000000u) : ~k;
    return __uint_as_float(u);
}
__device__ __forceinline__ int key_flat(u64 key) {
    return 2047 - (int)(key & 2047u);
}
__device__ __forceinline__ u64 max64(u64 a, u64 b) { return a > b ? a : b; }
__device__ __forceinline__ u64 min64(u64 a, u64 b) { return a < b ? a : b; }

// Bitonic sort of 16 register-resident u64 keys, descending (overflow fallback).
__device__ __forceinline__ void sort16_desc_u64(u64 (&a)[BEAM]) {
    #pragma unroll
    for (int k = 2; k <= 16; k <<= 1) {
        #pragma unroll
        for (int j = k >> 1; j > 0; j >>= 1) {
            #pragma unroll
            for (int i = 0; i < 16; ++i) {
                int l = i ^ j;
                if (l > i) {
                    const bool desc = ((i & k) == 0);
                    u64 x = a[i], y = a[l];
                    bool sw = desc ? (x < y) : (x > y);
                    a[i] = sw ? y : x;
                    a[l] = sw ? x : y;
                }
            }
        }
    }
}

// Bitonic sort of 16 register-resident f32 values, descending.
__device__ __forceinline__ void sort16_desc_f32(float (&a)[BEAM]) {
    #pragma unroll
    for (int k = 2; k <= 16; k <<= 1) {
        #pragma unroll
        for (int j = k >> 1; j > 0; j >>= 1) {
            #pragma unroll
            for (int i = 0; i < 16; ++i) {
                int l = i ^ j;
                if (l > i) {
                    const bool desc = ((i & k) == 0);
                    float x = a[i], y = a[l];
                    float mx = fmaxf(x, y), mn = fminf(x, y);
                    a[i] = desc ? mx : mn;
                    a[l] = desc ? mn : mx;
                }
            }
        }
    }
}

// One value-only butterfly merge level (exact-phase-1 fallback).
template <int M>
__device__ __forceinline__ void bf_level_f32(float (&a)[BEAM]) {
    float c[BEAM];
    #pragma unroll
    for (int i = 0; i < BEAM; ++i)
        c[i] = __shfl_xor(a[BEAM - 1 - i], M, 64);
    #pragma unroll
    for (int i = 0; i < BEAM; ++i)
        c[i] = fmaxf(a[i], c[i]);
    #pragma unroll
    for (int j = 8; j > 0; j >>= 1) {
        #pragma unroll
        for (int i = 0; i < BEAM; ++i)
            if ((i & j) == 0) {
                float x = c[i], y = c[i | j];
                c[i]     = fmaxf(x, y);
                c[i | j] = fminf(x, y);
            }
    }
    #pragma unroll
    for (int i = 0; i < BEAM; ++i) a[i] = c[i];
}

// Fully parallel log-softmax precompute: one 64-lane block per (t,b) row.
// Also emits rowmax = max_c logp = -log(sum) for the beam kernel's anchor.
__global__ __launch_bounds__(64) void softmax_kernel(const float* __restrict__ data,
                                                     float* __restrict__ lp_out,
                                                     float* __restrict__ rm_out) {
    const int row = blockIdx.x;
    const int lane = threadIdx.x;
    float x = data[row * NC + lane];
    float mx = x;
    #pragma unroll
    for (int m = 1; m < 64; m <<= 1) mx = fmaxf(mx, __shfl_xor(mx, m, 64));
    float sum = expf(x - mx);
    #pragma unroll
    for (int m = 1; m < 64; m <<= 1) sum += __shfl_xor(sum, m, 64);
    float ls = logf(sum);
    lp_out[row * NC + lane] = (x - mx) - ls;
    if (lane == 0) rm_out[row] = -ls;
}

template <bool PRE>
__global__ __launch_bounds__(64, 1) void ctc_beam_kernel(
        const float* __restrict__ data,      // [T, B, C] logits
        const float* __restrict__ lp_pre,    // [T, B, C] log-probs (if PRE)
        const float* __restrict__ rm_pre,    // [T, B] row max logp (if PRE)
        const int*   __restrict__ data_len,  // [B]
        float*       __restrict__ out)       // [B*4 probs][B*4 lens][B*4*256 labels]
{
    const int b    = blockIdx.x;
    const int lane = threadIdx.x;

    __shared__ __align__(16) u64 slotsL[128];     // [0,64) slots; [64,128) per-lane dump
    __shared__ unsigned short hist[T_MAX * BEAM]; // [11:8]=parent, bit7=stay, [6:0]=char
    __shared__ int ord4[TOPK];
    __shared__ float val4[TOPK];

    int len = data_len[b];
    if (len < 0) len = 0;
    if (len > T_MAX) len = T_MAX;

    // ---- beam state in registers (meaningful in lanes < 16) ----
    float pb  = (lane == 0) ? 0.0f : NEG;
    float pnb = NEG;
    float tot = log_add_exp(pb, pnb);  // carried; inside loop tot == val (bit-exact)
    u32 h1 = 0u, h2 = 0u;        // full prefix hash
    u32 ph1 = 0u, ph2 = 0u;      // hash of prefix minus last char
    int lenb = 0, lastb = -1;
    float spread = 1.0e30f;      // forces exact path at t=0
    float v1prev = 0.0f;

    const float* src = PRE ? lp_pre : data;
    float xpref = (len > 0) ? src[b * NC + lane] : 0.f;          // prefetch row 0
    float rmpref = (PRE && len > 0) ? rm_pre[b] : 0.f;           // rowmax[0,b]

    #pragma unroll 1
    for (int t = 0; t < len; ++t) {
        float x = xpref;
        float rm = rmpref;
        int tn = (t + 1 < len) ? (t + 1) : t;
        xpref = src[(tn * BATCH + b) * NC + lane];   // prefetch next row early
        if (PRE) rmpref = rm_pre[tn * BATCH + b];

        // pre-clear selection slots: drains under the long VALU phase below;
        // after a good scatter, slots [totc,64) are null with no pad stage.
        slotsL[lane] = 0ull;

        float lp;
        if (PRE) {
            lp = x;
        } else {
            float mx = x;
            #pragma unroll
            for (int m = 1; m < 64; m <<= 1) mx = fmaxf(mx, __shfl_xor(mx, m, 64));
            float sum = expf(x - mx);
            #pragma unroll
            for (int m = 1; m < 64; m <<= 1) sum += __shfl_xor(sum, m, 64);
            float ls = logf(sum);
            lp = (x - mx) - ls;
            rm = -ls;
        }
        float lp0 = rdl_f(lp, 0);

        // ---- stay candidates (lanes < 16 meaningful) ----
        int lastc = (lastb < 0) ? 0 : (lastb & 63);
        float lplast = __shfl(lp, lastc, 64);        // variable lane: bpermute
        float st_pb   = tot + lp0;
        float st_pnb0 = (lenb > 0) ? (pnb + lplast) : NEG;

        // packed broadcast word: h2 low 26 bits | lastb in [31:26]
        u32 p2 = (h2 & 0x03FFFFFFu) | ((u32)(lastb & 63) << 26);
        u32 ph2m = ph2 & 0x03FFFFFFu;
        float lpx = (lane == 0) ? BIGNEG : lp;       // blank-ext gate, hoisted

        // ---- fused per-beam loop: extends + parent-hash match ----
        float e0s[BEAM];
        int mi = -1;
        #pragma unroll
        for (int i = 0; i < BEAM; ++i) {
            float tot_i = rdl_f(tot, i);
            float pb_i  = rdl_f(pb, i);
            u32   h1_i  = rdl_u32(h1, i);
            u32   p2_i  = rdl_u32(p2, i);
            int last_i = (int)(p2_i >> 26);
            float e0  = tot_i + lpx;
            float e0f = pb_i + lpx;
            e0s[i] = (lane == last_i) ? e0f : e0;
            if (ph1 == h1_i && ph2m == (p2_i & 0x03FFFFFFu)) mi = i;
        }

        // ---- duplicate-prefix fold: sparse wave-uniform loop ----
        bool jm = (lane < BEAM) && (lenb > 0) && (mi >= 0);
        u64 mm = __ballot(jm);
        float merged = NEG;
        float st_pnb;
        if (mm) {
            u32 excl = 0u;
            int mpack = ((mi & 15) << 6) | (lastb & 63);
            u64 mw = mm;
            while (mw) {
                int j = (int)__builtin_ctzll(mw);
                mw &= mw - 1;
                int pk = rdl_i(mpack, j);            // dynamic uniform lane
                int i  = (pk >> 6) & 15;
                int c  = pk & 63;
                float tot_i = rdl_f(tot, i);
                float pb_i  = rdl_f(pb, i);
                int   l_i   = rdl_i(lastb, i);
                float lp_c  = rdl_f(lp, c);
                float mv = ((c == l_i) ? pb_i : tot_i) + lp_c;  // == e0s[i]@lane c
                if (lane == j) merged = mv;
                if (lane == c) excl |= (1u << i);    // exclude ext(i,c)
            }
            #pragma unroll
            for (int s = 0; s < BEAM; ++s)
                if ((excl >> s) & 1u) e0s[s] = BIGNEG;
            st_pnb = log_add_exp(st_pnb0, merged);
        } else {
            st_pnb = st_pnb0;   // lae(x, NEG) == x bit-exact for real x
        }
        float st_tot = log_add_exp(st_pb, st_pnb);

        // ---- fused speculative scatter: count + prefix + scatter, one pass.
        //      Non-survivors/overflow steered to per-lane dump slot 64+lane
        //      (distinct addresses, conflict-free). ----
        auto do_scatter = [&](float th) -> u32 {
            u32 mycnt = 0;
            #pragma unroll
            for (int s = 0; s < BEAM; ++s) mycnt += (e0s[s] >= th) ? 1u : 0u;
            bool stw = (lane < BEAM) && (st_tot >= th);
            mycnt += stw ? 1u : 0u;
            u32 base = 0;
            #pragma unroll
            for (int k = 0; k < 5; ++k)
                base += mbcnt64(__ballot(((mycnt >> k) & 1u) != 0u)) << k;
            u32 totc = rdl_u32(base + mycnt, 63);
            u32 pos = base;
            u32 dump = (64u + (u32)lane) << 3;
            u32 fl = 2031u - (u32)lane;          // 2047 - (BEAM + 0*NC + lane)
            #pragma unroll
            for (int s = 0; s < BEAM; ++s) {
                bool w = (e0s[s] >= th) && (pos < 64u);
                u32 a = w ? (pos << 3) : dump;
                *(u64*)((char*)slotsL + a) = pack_key_fl(e0s[s], fl);
                pos += (e0s[s] >= th) ? 1u : 0u;
                fl -= 64u;
            }
            {
                u32 a = (stw && pos < 64u) ? (pos << 3) : dump;
                *(u64*)((char*)slotsL + a) = pack_key_fl(st_tot, 2047u - (u32)lane);
            }
            return totc;
        };

        float A = v1prev + rm;
        u32 totc = do_scatter(A - spread);
        if (totc < BEAM || totc > 32u) {
            float th2 = (totc > 32u) ? (A - 0.45f * spread)
                                     : (A - (2.5f * spread + 1.0f));
            slotsL[lane] = 0ull;                 // re-clear stale survivors
            asm volatile("" ::: "memory");
            totc = do_scatter(th2);
            if (totc < BEAM || totc > 32u) {
                // ---- exact phase-1: v16 = 16th-largest of the true multiset ----
                float a[BEAM];
                #pragma unroll
                for (int s = 0; s < BEAM; ++s) a[s] = e0s[s];
                sort16_desc_f32(a);
                {   // fold stay value into local sorted list
                    float sv = (lane < BEAM) ? st_tot : NEG;
                    #pragma unroll
                    for (int i = BEAM - 1; i >= 1; --i)
                        a[i] = fmaxf(a[i], fminf(a[i - 1], sv));
                    a[0] = fmaxf(a[0], sv);
                }
                bf_level_f32<1>(a);  bf_level_f32<2>(a);  bf_level_f32<4>(a);
                bf_level_f32<8>(a);  bf_level_f32<16>(a); bf_level_f32<32>(a);
                slotsL[lane] = 0ull;             // re-clear stale survivors
                asm volatile("" ::: "memory");
                totc = do_scatter(a[15]);        // totc in [16,32] by construction
            }
        }

        int flat; float val;
        if (totc <= 32u) {
            asm volatile("" ::: "memory");   // single wave: in-order LDS
            u64 mk = slotsL[lane];
            u32 rank = 0;                    // #keys strictly greater
            const uint4* q4 = (const uint4*)slotsL;
            if (totc <= 16u) {               // slots 16-31 provably null
                #pragma unroll
                for (int q = 0; q < 8; ++q) {
                    uint4 w = q4[q];
                    u64 ka = ((u64)w.y << 32) | w.x;
                    u64 kb = ((u64)w.w << 32) | w.z;
                    rank += (ka > mk) ? 1u : 0u;
                    rank += (kb > mk) ? 1u : 0u;
                }
            } else {
                #pragma unroll
                for (int q = 0; q < 16; ++q) {   // 32 keys = 16 x 16B
                    uint4 w = q4[q];
                    u64 ka = ((u64)w.y << 32) | w.x;
                    u64 kb = ((u64)w.w << 32) | w.z;
                    rank += (ka > mk) ? 1u : 0u;
                    rank += (kb > mk) ? 1u : 0u;
                }
            }
            // push-by-rank: lane r receives the rank-r key (ranks unique,
            // keys strictly distinct via flat tie-break)
            int selhi = 0, sello = 0;
            if (lane < (int)totc) {
                selhi = __builtin_amdgcn_ds_permute((int)(rank << 2),
                                                    (int)(mk >> 32));
                sello = __builtin_amdgcn_ds_permute((int)(rank << 2),
                                                    (int)(mk & 0xFFFFFFFFu));
            }
            u64 sel = ((u64)(u32)selhi << 32) | (u32)sello;
            flat = key_flat(sel);
            val  = key_val(sel);
        } else {
            // ---- exact u64 register fallback (tie storm), ~never ----
            u64 ku[BEAM];
            #pragma unroll
            for (int s = 0; s < BEAM; ++s)
                ku[s] = pack_key(e0s[s], BEAM + s * NC + lane);
            sort16_desc_u64(ku);
            u64 sk = (lane < BEAM) ? pack_key(st_tot, lane) : 0ull;
            #pragma unroll
            for (int i = BEAM - 1; i >= 1; --i)
                ku[i] = max64(ku[i], min64(ku[i - 1], sk));
            ku[0] = max64(ku[0], sk);
            #pragma unroll 1
            for (int m = 1; m < 64; m <<= 1) {
                u64 c_[BEAM];
                #pragma unroll
                for (int i = 0; i < BEAM; ++i) {
                    u64 o = (u64)__shfl_xor((long long)ku[BEAM - 1 - i], m, 64);
                    c_[i] = max64(ku[i], o);
                }
                #pragma unroll
                for (int j = 8; j > 0; j >>= 1) {
                    #pragma unroll
                    for (int i = 0; i < BEAM; ++i)
                        if ((i & j) == 0) {
                            u64 xk = c_[i], yk = c_[i | j];
                            bool sw = xk < yk;
                            c_[i]     = sw ? yk : xk;
                            c_[i | j] = sw ? xk : yk;
                        }
                }
                #pragma unroll
                for (int i = 0; i < BEAM; ++i) ku[i] = c_[i];
            }
            u64 selkey = ku[0];
            #pragma unroll
            for (int i = 1; i < BEAM; ++i)
                if (lane == i) selkey = ku[i];
            flat = key_flat(selkey);
            val  = key_val(selkey);
        }

        // ---- predictor update from the EXACT selection (any path) ----
        {
            float v1n  = rdl_f(val, 0);
            float v16n = rdl_f(val, 15);
            spread = (fmaxf(A, v1n) - v16n) * 1.25f + 1.0e-3f;
            v1prev = v1n;
        }

        // ---- new state (lane k = rank-k winner) ----
        bool stay = flat < BEAM;
        int pidx = (stay ? flat : ((flat - BEAM) >> 6)) & 15;
        int cnew = stay ? 0 : ((flat - BEAM) & 63);

        // variable-index gathers (bpermute), all independent -> one wait
        float g_stpb  = __shfl(st_pb, pidx, 64);
        float g_stpnb = __shfl(st_pnb, pidx, 64);
        u32   g_h1    = (u32)__shfl((int)h1, pidx, 64);
        u32   g_h2    = (u32)__shfl((int)h2, pidx, 64);
        u32   g_ph1   = (u32)__shfl((int)ph1, pidx, 64);
        u32   g_ph2   = (u32)__shfl((int)ph2, pidx, 64);
        int   g_ll    = __shfl((lenb << 8) | (lastb & 255), pidx, 64);
        int   g_len   = g_ll >> 8;
        int   g_last  = (int)(signed char)(g_ll & 255);

        pb   = stay ? g_stpb : NEG;
        pnb  = stay ? g_stpnb : val;
        tot  = val;                      // == lae(pb,pnb) bit-exactly
        ph1  = stay ? g_ph1 : g_h1;      // parent-hash of new prefix
        ph2  = stay ? g_ph2 : g_h2;
        h1   = stay ? g_h1 : (g_h1 * 1000003u + (u32)(cnew + 1));
        h2   = stay ? g_h2 : (g_h2 * 69069u   + (u32)(cnew + 1));
        lenb = g_len + (stay ? 0 : 1);
        lastb = stay ? g_last : cnew;
        if (lane < BEAM)
            hist[t * BEAM + lane] =
                (unsigned short)((pidx << 8) | (stay ? 0x80 : 0) | cnew);
    }
    __syncthreads();

    // ---- final stable top-4 over beam totals ----
    float ft = (lane < BEAM) ? log_add_exp(pb, pnb) : -FLTMAX;
    int fidx = (lane < BEAM) ? lane : 0x7FFFFFFF;
    for (int k = 0; k < TOPK; ++k) {
        float bv = ft; int bi = fidx;
        #pragma unroll
        for (int m = 1; m < 64; m <<= 1) {
            float ov = __shfl_xor(bv, m, 64);
            int   oi = __shfl_xor(bi, m, 64);
            if (ov > bv || (ov == bv && oi < bi)) { bv = ov; bi = oi; }
        }
        if (lane == 0) { ord4[k] = bi; val4[k] = bv; }
        if (lane == bi) ft = -FLTMAX;
    }
    __syncthreads();

    int bsel = ord4[lane & 3] & 15;
    int lensel = __shfl(lenb, bsel, 64);

    // ---- outputs: probs [B,4] | lens [B,4] | labels [B,4,256] ----
    for (int e2 = lane; e2 < TOPK * T_MAX; e2 += 64)
        out[BATCH * TOPK * 2 + b * (TOPK * T_MAX) + e2] = -1.0f;
    __syncthreads();
    if (lane < TOPK) {
        const int k = lane;
        out[b * TOPK + k] = -val4[k];
        out[BATCH * TOPK + b * TOPK + k] = (float)lensel;
        int pos = lensel - 1;
        int cur = ord4[k];
        float* lab = out + BATCH * TOPK * 2 + b * (TOPK * T_MAX) + k * T_MAX;
        for (int tt = len - 1; tt >= 0; --tt) {
            unsigned short h = hist[tt * BEAM + cur];
            if (!(h & 0x80)) { lab[pos] = (float)(h & 0x7F); --pos; }
            cur = h >> 8;
        }
    }
}

extern "C" void kernel_launch(void* const* d_in, const int* in_sizes, int n_in,
                              void* d_out, int out_size, void* d_ws, size_t ws_size,
                              hipStream_t stream) {
    const float* data = (const float*)d_in[0];
    const int* data_len = (const int*)d_in[1];
    float* out = (float*)d_out;
    const size_t lp_bytes = (size_t)T_MAX * BATCH * NC * sizeof(float);
    const size_t rm_bytes = (size_t)T_MAX * BATCH * sizeof(float);
    if (ws_size >= lp_bytes + rm_bytes) {
        float* lp_ws = (float*)d_ws;
        float* rm_ws = lp_ws + (size_t)T_MAX * BATCH * NC;
        softmax_kernel<<<dim3(T_MAX * BATCH), dim3(64), 0, stream>>>(data, lp_ws, rm_ws);
        ctc_beam_kernel<true><<<dim3(BATCH), dim3(64), 0, stream>>>(data, lp_ws, rm_ws, data_len, out);
    } else {
        ctc_beam_kernel<false><<<dim3(BATCH), dim3(64), 0, stream>>>(data, nullptr, nullptr, data_len, out);
    }
}

// Round 12
// 588.871 us; speedup vs baseline: 1.1688x; 1.0020x over previous
//
#include <hip/hip_runtime.h>

// CTC prefix beam search, MI355X. One wave per batch element; latency-bound
// serial scan. R12 = R9 (proven best, 537us kernel, reconfirmed R11) +
// block-layout-only hints -- NO instruction-mix changes in the hot path:
//   (a) __builtin_expect on the retry / exact-phase-1 / fallback guards
//       (cold: predictor hit rate is high -- conflict counter shows retries
//       are rare) so the compiler sinks those large cold bodies out of the
//       sequential fetch stream of the ~10KB hot loop.
//   (b) s_setprio(1) once at kernel entry (free at 1 wave/CU).
// Rationale: R6/R7/R8/R10 showed theory-neutral restructurings move wall
// time +/-15% via codegen scheduling; R9's instruction mix is a verified
// schedule-local optimum, so only zero-mix-perturbation edits remain.
// Structure (R9): pre-clear slots + per-lane dump slots + half-rank +
// tot=val carry + fused speculative scatter + sparse merge loop +
// rank-selection via LDS broadcast compare + ds_permute push-by-rank +
// exact u64 register-sort fallback.
// Exactness: selection is the exact stable top-16 (pack_key tie-break =
// lax.top_k order); merged is bit-identical (1-element logsumexp = value).

#define T_MAX 256
#define BATCH 32
#define NC 64
#define BEAM 16
#define TOPK 4
#define NEG (-1.0e9f)
#define BIGNEG (-2.0e9f)
#define FLTMAX 3.402823466e+38f

typedef unsigned long long u64;
typedef unsigned int u32;

// Matches jnp.logaddexp exactly: max + log1p(exp(-|a-b|))
__device__ __forceinline__ float log_add_exp(float a, float b) {
    float m = fmaxf(a, b);
    float d = fabsf(a - b);
    return m + log1pf(expf(-d));
}

// Wave-uniform lane reads: VALU->SGPR, no DS pipe.
__device__ __forceinline__ u32 rdl_u32(u32 v, int sl) {
    return (u32)__builtin_amdgcn_readlane((int)v, sl);
}
__device__ __forceinline__ float rdl_f(float v, int sl) {
    return __uint_as_float(rdl_u32(__float_as_uint(v), sl));
}
__device__ __forceinline__ int rdl_i(int v, int sl) {
    return __builtin_amdgcn_readlane(v, sl);
}
// popcount of 64-bit mask strictly below this lane
__device__ __forceinline__ u32 mbcnt64(u64 m) {
    return __builtin_amdgcn_mbcnt_hi((u32)(m >> 32),
           __builtin_amdgcn_mbcnt_lo((u32)m, 0u));
}

// u64 key: monotone float in [42:11], fl = 2047-flat in [10:0].
// Larger key == (larger value, then smaller flat) -> lax.top_k stable order.
// All real keys > 0, so 0 is a safe null (sinks in descending order).
__device__ __forceinline__ u64 pack_key_fl(float v, u32 fl) {
    u32 u = __float_as_uint(v);
    u32 m = u ^ ((u32)((int)u >> 31) | 0x80000000u);
    return ((u64)m << 11) | (u64)fl;
}
__device__ __forceinline__ u64 pack_key(float v, int flat) {
    return pack_key_fl(v, (u32)(2047 - flat));
}
__device__ __forceinline__ float key_val(u64 key) {
    u32 k = (u32)(key >> 11);
    u32 u = (k & 0x80000000u) ? (k ^ 0x80000000u) : ~k;
    return __uint_as_float(u);
}
__device__ __forceinline__ int key_flat(u64 key) {
    return 2047 - (int)(key & 2047u);
}
__device__ __forceinline__ u64 max64(u64 a, u64 b) { return a > b ? a : b; }
__device__ __forceinline__ u64 min64(u64 a, u64 b) { return a < b ? a : b; }

// Bitonic sort of 16 register-resident u64 keys, descending (overflow fallback).
__device__ __forceinline__ void sort16_desc_u64(u64 (&a)[BEAM]) {
    #pragma unroll
    for (int k = 2; k <= 16; k <<= 1) {
        #pragma unroll
        for (int j = k >> 1; j > 0; j >>= 1) {
            #pragma unroll
            for (int i = 0; i < 16; ++i) {
                int l = i ^ j;
                if (l > i) {
                    const bool desc = ((i & k) == 0);
                    u64 x = a[i], y = a[l];
                    bool sw = desc ? (x < y) : (x > y);
                    a[i] = sw ? y : x;
                    a[l] = sw ? x : y;
                }
            }
        }
    }
}

// Bitonic sort of 16 register-resident f32 values, descending.
__device__ __forceinline__ void sort16_desc_f32(float (&a)[BEAM]) {
    #pragma unroll
    for (int k = 2; k <= 16; k <<= 1) {
        #pragma unroll
        for (int j = k >> 1; j > 0; j >>= 1) {
            #pragma unroll
            for (int i = 0; i < 16; ++i) {
                int l = i ^ j;
                if (l > i) {
                    const bool desc = ((i & k) == 0);
                    float x = a[i], y = a[l];
                    float mx = fmaxf(x, y), mn = fminf(x, y);
                    a[i] = desc ? mx : mn;
                    a[l] = desc ? mn : mx;
                }
            }
        }
    }
}

// One value-only butterfly merge level (exact-phase-1 fallback).
template <int M>
__device__ __forceinline__ void bf_level_f32(float (&a)[BEAM]) {
    float c[BEAM];
    #pragma unroll
    for (int i = 0; i < BEAM; ++i)
        c[i] = __shfl_xor(a[BEAM - 1 - i], M, 64);
    #pragma unroll
    for (int i = 0; i < BEAM; ++i)
        c[i] = fmaxf(a[i], c[i]);
    #pragma unroll
    for (int j = 8; j > 0; j >>= 1) {
        #pragma unroll
        for (int i = 0; i < BEAM; ++i)
            if ((i & j) == 0) {
                float x = c[i], y = c[i | j];
                c[i]     = fmaxf(x, y);
                c[i | j] = fminf(x, y);
            }
    }
    #pragma unroll
    for (int i = 0; i < BEAM; ++i) a[i] = c[i];
}

// Fully parallel log-softmax precompute: one 64-lane block per (t,b) row.
// Also emits rowmax = max_c logp = -log(sum) for the beam kernel's anchor.
__global__ __launch_bounds__(64) void softmax_kernel(const float* __restrict__ data,
                                                     float* __restrict__ lp_out,
                                                     float* __restrict__ rm_out) {
    const int row = blockIdx.x;
    const int lane = threadIdx.x;
    float x = data[row * NC + lane];
    float mx = x;
    #pragma unroll
    for (int m = 1; m < 64; m <<= 1) mx = fmaxf(mx, __shfl_xor(mx, m, 64));
    float sum = expf(x - mx);
    #pragma unroll
    for (int m = 1; m < 64; m <<= 1) sum += __shfl_xor(sum, m, 64);
    float ls = logf(sum);
    lp_out[row * NC + lane] = (x - mx) - ls;
    if (lane == 0) rm_out[row] = -ls;
}

template <bool PRE>
__global__ __launch_bounds__(64, 1) void ctc_beam_kernel(
        const float* __restrict__ data,      // [T, B, C] logits
        const float* __restrict__ lp_pre,    // [T, B, C] log-probs (if PRE)
        const float* __restrict__ rm_pre,    // [T, B] row max logp (if PRE)
        const int*   __restrict__ data_len,  // [B]
        float*       __restrict__ out)       // [B*4 probs][B*4 lens][B*4*256 labels]
{
    const int b    = blockIdx.x;
    const int lane = threadIdx.x;

    __builtin_amdgcn_s_setprio(1);

    __shared__ __align__(16) u64 slotsL[128];     // [0,64) slots; [64,128) per-lane dump
    __shared__ unsigned short hist[T_MAX * BEAM]; // [11:8]=parent, bit7=stay, [6:0]=char
    __shared__ int ord4[TOPK];
    __shared__ float val4[TOPK];

    int len = data_len[b];
    if (len < 0) len = 0;
    if (len > T_MAX) len = T_MAX;

    // ---- beam state in registers (meaningful in lanes < 16) ----
    float pb  = (lane == 0) ? 0.0f : NEG;
    float pnb = NEG;
    float tot = log_add_exp(pb, pnb);  // carried; inside loop tot == val (bit-exact)
    u32 h1 = 0u, h2 = 0u;        // full prefix hash
    u32 ph1 = 0u, ph2 = 0u;      // hash of prefix minus last char
    int lenb = 0, lastb = -1;
    float spread = 1.0e30f;      // forces exact path at t=0
    float v1prev = 0.0f;

    const float* src = PRE ? lp_pre : data;
    float xpref = (len > 0) ? src[b * NC + lane] : 0.f;          // prefetch row 0
    float rmpref = (PRE && len > 0) ? rm_pre[b] : 0.f;           // rowmax[0,b]

    #pragma unroll 1
    for (int t = 0; t < len; ++t) {
        float x = xpref;
        float rm = rmpref;
        int tn = (t + 1 < len) ? (t + 1) : t;
        xpref = src[(tn * BATCH + b) * NC + lane];   // prefetch next row early
        if (PRE) rmpref = rm_pre[tn * BATCH + b];

        // pre-clear selection slots: drains under the long VALU phase below;
        // after a good scatter, slots [totc,64) are null with no pad stage.
        slotsL[lane] = 0ull;

        float lp;
        if (PRE) {
            lp = x;
        } else {
            float mx = x;
            #pragma unroll
            for (int m = 1; m < 64; m <<= 1) mx = fmaxf(mx, __shfl_xor(mx, m, 64));
            float sum = expf(x - mx);
            #pragma unroll
            for (int m = 1; m < 64; m <<= 1) sum += __shfl_xor(sum, m, 64);
            float ls = logf(sum);
            lp = (x - mx) - ls;
            rm = -ls;
        }
        float lp0 = rdl_f(lp, 0);

        // ---- stay candidates (lanes < 16 meaningful) ----
        int lastc = (lastb < 0) ? 0 : (lastb & 63);
        float lplast = __shfl(lp, lastc, 64);        // variable lane: bpermute
        float st_pb   = tot + lp0;
        float st_pnb0 = (lenb > 0) ? (pnb + lplast) : NEG;

        // packed broadcast word: h2 low 26 bits | lastb in [31:26]
        u32 p2 = (h2 & 0x03FFFFFFu) | ((u32)(lastb & 63) << 26);
        u32 ph2m = ph2 & 0x03FFFFFFu;
        float lpx = (lane == 0) ? BIGNEG : lp;       // blank-ext gate, hoisted

        // ---- fused per-beam loop: extends + parent-hash match ----
        float e0s[BEAM];
        int mi = -1;
        #pragma unroll
        for (int i = 0; i < BEAM; ++i) {
            float tot_i = rdl_f(tot, i);
            float pb_i  = rdl_f(pb, i);
            u32   h1_i  = rdl_u32(h1, i);
            u32   p2_i  = rdl_u32(p2, i);
            int last_i = (int)(p2_i >> 26);
            float e0  = tot_i + lpx;
            float e0f = pb_i + lpx;
            e0s[i] = (lane == last_i) ? e0f : e0;
            if (ph1 == h1_i && ph2m == (p2_i & 0x03FFFFFFu)) mi = i;
        }

        // ---- duplicate-prefix fold: sparse wave-uniform loop ----
        bool jm = (lane < BEAM) && (lenb > 0) && (mi >= 0);
        u64 mm = __ballot(jm);
        float merged = NEG;
        float st_pnb;
        if (mm) {
            u32 excl = 0u;
            int mpack = ((mi & 15) << 6) | (lastb & 63);
            u64 mw = mm;
            while (mw) {
                int j = (int)__builtin_ctzll(mw);
                mw &= mw - 1;
                int pk = rdl_i(mpack, j);            // dynamic uniform lane
                int i  = (pk >> 6) & 15;
                int c  = pk & 63;
                float tot_i = rdl_f(tot, i);
                float pb_i  = rdl_f(pb, i);
                int   l_i   = rdl_i(lastb, i);
                float lp_c  = rdl_f(lp, c);
                float mv = ((c == l_i) ? pb_i : tot_i) + lp_c;  // == e0s[i]@lane c
                if (lane == j) merged = mv;
                if (lane == c) excl |= (1u << i);    // exclude ext(i,c)
            }
            #pragma unroll
            for (int s = 0; s < BEAM; ++s)
                if ((excl >> s) & 1u) e0s[s] = BIGNEG;
            st_pnb = log_add_exp(st_pnb0, merged);
        } else {
            st_pnb = st_pnb0;   // lae(x, NEG) == x bit-exact for real x
        }
        float st_tot = log_add_exp(st_pb, st_pnb);

        // ---- fused speculative scatter: count + prefix + scatter, one pass.
        //      Non-survivors/overflow steered to per-lane dump slot 64+lane
        //      (distinct addresses, conflict-free). ----
        auto do_scatter = [&](float th) -> u32 {
            u32 mycnt = 0;
            #pragma unroll
            for (int s = 0; s < BEAM; ++s) mycnt += (e0s[s] >= th) ? 1u : 0u;
            bool stw = (lane < BEAM) && (st_tot >= th);
            mycnt += stw ? 1u : 0u;
            u32 base = 0;
            #pragma unroll
            for (int k = 0; k < 5; ++k)
                base += mbcnt64(__ballot(((mycnt >> k) & 1u) != 0u)) << k;
            u32 totc = rdl_u32(base + mycnt, 63);
            u32 pos = base;
            u32 dump = (64u + (u32)lane) << 3;
            u32 fl = 2031u - (u32)lane;          // 2047 - (BEAM + 0*NC + lane)
            #pragma unroll
            for (int s = 0; s < BEAM; ++s) {
                bool w = (e0s[s] >= th) && (pos < 64u);
                u32 a = w ? (pos << 3) : dump;
                *(u64*)((char*)slotsL + a) = pack_key_fl(e0s[s], fl);
                pos += (e0s[s] >= th) ? 1u : 0u;
                fl -= 64u;
            }
            {
                u32 a = (stw && pos < 64u) ? (pos << 3) : dump;
                *(u64*)((char*)slotsL + a) = pack_key_fl(st_tot, 2047u - (u32)lane);
            }
            return totc;
        };

        float A = v1prev + rm;
        u32 totc = do_scatter(A - spread);
        if (__builtin_expect(totc < BEAM || totc > 32u, 0)) {
            float th2 = (totc > 32u) ? (A - 0.45f * spread)
                                     : (A - (2.5f * spread + 1.0f));
            slotsL[lane] = 0ull;                 // re-clear stale survivors
            asm volatile("" ::: "memory");
            totc = do_scatter(th2);
            if (__builtin_expect(totc < BEAM || totc > 32u, 0)) {
                // ---- exact phase-1: v16 = 16th-largest of the true multiset ----
                float a[BEAM];
                #pragma unroll
                for (int s = 0; s < BEAM; ++s) a[s] = e0s[s];
                sort16_desc_f32(a);
                {   // fold stay value into local sorted list
                    float sv = (lane < BEAM) ? st_tot : NEG;
                    #pragma unroll
                    for (int i = BEAM - 1; i >= 1; --i)
                        a[i] = fmaxf(a[i], fminf(a[i - 1], sv));
                    a[0] = fmaxf(a[0], sv);
                }
                bf_level_f32<1>(a);  bf_level_f32<2>(a);  bf_level_f32<4>(a);
                bf_level_f32<8>(a);  bf_level_f32<16>(a); bf_level_f32<32>(a);
                slotsL[lane] = 0ull;             // re-clear stale survivors
                asm volatile("" ::: "memory");
                totc = do_scatter(a[15]);        // totc in [16,32] by construction
            }
        }

        int flat; float val;
        if (__builtin_expect(totc <= 32u, 1)) {
            asm volatile("" ::: "memory");   // single wave: in-order LDS
            u64 mk = slotsL[lane];
            u32 rank = 0;                    // #keys strictly greater
            const uint4* q4 = (const uint4*)slotsL;
            if (totc <= 16u) {               // slots 16-31 provably null
                #pragma unroll
                for (int q = 0; q < 8; ++q) {
                    uint4 w = q4[q];
                    u64 ka = ((u64)w.y << 32) | w.x;
                    u64 kb = ((u64)w.w << 32) | w.z;
                    rank += (ka > mk) ? 1u : 0u;
                    rank += (kb > mk) ? 1u : 0u;
                }
            } else {
                #pragma unroll
                for (int q = 0; q < 16; ++q) {   // 32 keys = 16 x 16B
                    uint4 w = q4[q];
                    u64 ka = ((u64)w.y << 32) | w.x;
                    u64 kb = ((u64)w.w << 32) | w.z;
                    rank += (ka > mk) ? 1u : 0u;
                    rank += (kb > mk) ? 1u : 0u;
                }
            }
            // push-by-rank: lane r receives the rank-r key (ranks unique,
            // keys strictly distinct via flat tie-break)
            int selhi = 0, sello = 0;
            if (lane < (int)totc) {
                selhi = __builtin_amdgcn_ds_permute((int)(rank << 2),
                                                    (int)(mk >> 32));
                sello = __builtin_amdgcn_ds_permute((int)(rank << 2),
                                                    (int)(mk & 0xFFFFFFFFu));
            }
            u64 sel = ((u64)(u32)selhi << 32) | (u32)sello;
            flat = key_flat(sel);
            val  = key_val(sel);
        } else {
            // ---- exact u64 register fallback (tie storm), ~never ----
            u64 ku[BEAM];
            #pragma unroll
            for (int s = 0; s < BEAM; ++s)
                ku[s] = pack_key(e0s[s], BEAM + s * NC + lane);
            sort16_desc_u64(ku);
            u64 sk = (lane < BEAM) ? pack_key(st_tot, lane) : 0ull;
            #pragma unroll
            for (int i = BEAM - 1; i >= 1; --i)
                ku[i] = max64(ku[i], min64(ku[i - 1], sk));
            ku[0] = max64(ku[0], sk);
            #pragma unroll 1
            for (int m = 1; m < 64; m <<= 1) {
                u64 c_[BEAM];
                #pragma unroll
                for (int i = 0; i < BEAM; ++i) {
                    u64 o = (u64)__shfl_xor((long long)ku[BEAM - 1 - i], m, 64);
                    c_[i] = max64(ku[i], o);
                }
                #pragma unroll
                for (int j = 8; j > 0; j >>= 1) {
                    #pragma unroll
                    for (int i = 0; i < BEAM; ++i)
                        if ((i & j) == 0) {
                            u64 xk = c_[i], yk = c_[i | j];
                            bool sw = xk < yk;
                            c_[i]     = sw ? yk : xk;
                            c_[i | j] = sw ? xk : yk;
                        }
                }
                #pragma unroll
                for (int i = 0; i < BEAM; ++i) ku[i] = c_[i];
            }
            u64 selkey = ku[0];
            #pragma unroll
            for (int i = 1; i < BEAM; ++i)
                if (lane == i) selkey = ku[i];
            flat = key_flat(selkey);
            val  = key_val(selkey);
        }

        // ---- predictor update from the EXACT selection (any path) ----
        {
            float v1n  = rdl_f(val, 0);
            float v16n = rdl_f(val, 15);
            spread = (fmaxf(A, v1n) - v16n) * 1.25f + 1.0e-3f;
            v1prev = v1n;
        }

        // ---- new state (lane k = rank-k winner) ----
        bool stay = flat < BEAM;
        int pidx = (stay ? flat : ((flat - BEAM) >> 6)) & 15;
        int cnew = stay ? 0 : ((flat - BEAM) & 63);

        // variable-index gathers (bpermute), all independent -> one wait
        float g_stpb  = __shfl(st_pb, pidx, 64);
        float g_stpnb = __shfl(st_pnb, pidx, 64);
        u32   g_h1    = (u32)__shfl((int)h1, pidx, 64);
        u32   g_h2    = (u32)__shfl((int)h2, pidx, 64);
        u32   g_ph1   = (u32)__shfl((int)ph1, pidx, 64);
        u32   g_ph2   = (u32)__shfl((int)ph2, pidx, 64);
        int   g_ll    = __shfl((lenb << 8) | (lastb & 255), pidx, 64);
        int   g_len   = g_ll >> 8;
        int   g_last  = (int)(signed char)(g_ll & 255);

        pb   = stay ? g_stpb : NEG;
        pnb  = stay ? g_stpnb : val;
        tot  = val;                      // == lae(pb,pnb) bit-exactly
        ph1  = stay ? g_ph1 : g_h1;      // parent-hash of new prefix
        ph2  = stay ? g_ph2 : g_h2;
        h1   = stay ? g_h1 : (g_h1 * 1000003u + (u32)(cnew + 1));
        h2   = stay ? g_h2 : (g_h2 * 69069u   + (u32)(cnew + 1));
        lenb = g_len + (stay ? 0 : 1);
        lastb = stay ? g_last : cnew;
        if (lane < BEAM)
            hist[t * BEAM + lane] =
                (unsigned short)((pidx << 8) | (stay ? 0x80 : 0) | cnew);
    }
    __syncthreads();

    // ---- final stable top-4 over beam totals ----
    float ft = (lane < BEAM) ? log_add_exp(pb, pnb) : -FLTMAX;
    int fidx = (lane < BEAM) ? lane : 0x7FFFFFFF;
    for (int k = 0; k < TOPK; ++k) {
        float bv = ft; int bi = fidx;
        #pragma unroll
        for (int m = 1; m < 64; m <<= 1) {
            float ov = __shfl_xor(bv, m, 64);
            int   oi = __shfl_xor(bi, m, 64);
            if (ov > bv || (ov == bv && oi < bi)) { bv = ov; bi = oi; }
        }
        if (lane == 0) { ord4[k] = bi; val4[k] = bv; }
        if (lane == bi) ft = -FLTMAX;
    }
    __syncthreads();

    int bsel = ord4[lane & 3] & 15;
    int lensel = __shfl(lenb, bsel, 64);

    // ---- outputs: probs [B,4] | lens [B,4] | labels [B,4,256] ----
    for (int e2 = lane; e2 < TOPK * T_MAX; e2 += 64)
        out[BATCH * TOPK * 2 + b * (TOPK * T_MAX) + e2] = -1.0f;
    __syncthreads();
    if (lane < TOPK) {
        const int k = lane;
        out[b * TOPK + k] = -val4[k];
        out[BATCH * TOPK + b * TOPK + k] = (float)lensel;
        int pos = lensel - 1;
        int cur = ord4[k];
        float* lab = out + BATCH * TOPK * 2 + b * (TOPK * T_MAX) + k * T_MAX;
        for (int tt = len - 1; tt >= 0; --tt) {
            unsigned short h = hist[tt * BEAM + cur];
            if (!(h & 0x80)) { lab[pos] = (float)(h & 0x7F); --pos; }
            cur = h >> 8;
        }
    }
}

extern "C" void kernel_launch(void* const* d_in, const int* in_sizes, int n_in,
                              void* d_out, int out_size, void* d_ws, size_t ws_size,
                              hipStream_t stream) {
    const float* data = (const float*)d_in[0];
    const int* data_len = (const int*)d_in[1];
    float* out = (float*)d_out;
    const size_t lp_bytes = (size_t)T_MAX * BATCH * NC * sizeof(float);
    const size_t rm_bytes = (size_t)T_MAX * BATCH * sizeof(float);
    if (ws_size >= lp_bytes + rm_bytes) {
        float* lp_ws = (float*)d_ws;
        float* rm_ws = lp_ws + (size_t)T_MAX * BATCH * NC;
        softmax_kernel<<<dim3(T_MAX * BATCH), dim3(64), 0, stream>>>(data, lp_ws, rm_ws);
        ctc_beam_kernel<true><<<dim3(BATCH), dim3(64), 0, stream>>>(data, lp_ws, rm_ws, data_len, out);
    } else {
        ctc_beam_kernel<false><<<dim3(BATCH), dim3(64), 0, stream>>>(data, nullptr, nullptr, data_len, out);
    }
}